// Round 8
// baseline (671.225 us; speedup 1.0000x reference)
//
#include <hip/hip_runtime.h>

#define D 128
#define NB 256          // counting-sort chunks (one block each)
#define Q 16            // sections for the b-dimension scan (prefix fits ushort)
#define BQ (NB / Q)     // blocks per section = 16
#define NBINS_MAX 10016 // max nodes supported by LDS histogram (~40 KB)
#define TROWS 16
// HW_REG_XCC_ID (id=20, offset=0, size=32) -> s_getreg imm encoding
#define XCC_ID_IMM (20 | (31 << 11))

// ---------------- fused per-chunk LDS histograms of dst and src ----------------
__global__ __launch_bounds__(256) void hist_kernel(const int* __restrict__ src, const int* __restrict__ dst,
                                                   unsigned short* __restrict__ pd, unsigned short* __restrict__ ps,
                                                   int E, int n) {
    __shared__ int hd[NBINS_MAX];
    __shared__ int hs[NBINS_MAX];
    int b = blockIdx.x, t = threadIdx.x;
    int chunk = (E + NB - 1) / NB;
    int e0 = b * chunk, e1 = min(e0 + chunk, E);
    for (int i = t; i < n; i += 256) { hd[i] = 0; hs[i] = 0; }
    __syncthreads();
    for (int e = e0 + t; e < e1; e += 256) {
        atomicAdd(&hd[dst[e]], 1);
        atomicAdd(&hs[src[e]], 1);
    }
    __syncthreads();
    for (int i = t; i < n; i += 256) {
        pd[(size_t)b * n + i] = (unsigned short)hd[i];
        ps[(size_t)b * n + i] = (unsigned short)hs[i];
    }
}

// ---------------- within-section exclusive scan of pd along b (in place, ushort) ----------------
__global__ __launch_bounds__(256) void colscan_kernel(unsigned short* __restrict__ pd,
                                                      const unsigned short* __restrict__ ps,
                                                      int* __restrict__ qtot_d, int* __restrict__ qtot_s, int n) {
    int bin = blockIdx.x * 256 + threadIdx.x;
    int q = blockIdx.y;
    if (bin >= n) return;
    int b0 = q * BQ;
    int run = 0, ssum = 0;
#pragma unroll
    for (int j = 0; j < BQ; ++j) {
        size_t idx = (size_t)(b0 + j) * n + bin;
        int v = (int)pd[idx];
        pd[idx] = (unsigned short)run;   // max 16*2500 = 40000 < 65536
        run += v;
        ssum += (int)ps[idx];
    }
    qtot_d[(size_t)q * n + bin] = run;
    qtot_s[(size_t)q * n + bin] = ssum;
}

// ---------------- per-bin: scan section totals -> bases; degrees -> norms ----------------
__global__ __launch_bounds__(256) void finalize_kernel(int* __restrict__ qtot_d /* becomes qbase */,
                                                       const int* __restrict__ qtot_s,
                                                       int* __restrict__ in_deg,
                                                       float* __restrict__ norm_src, float* __restrict__ norm_dst,
                                                       int n) {
    int bin = blockIdx.x * 256 + threadIdx.x;
    if (bin >= n) return;
    int run = 0;
#pragma unroll
    for (int q = 0; q < Q; ++q) {
        size_t i = (size_t)q * n + bin;
        int v = qtot_d[i];
        qtot_d[i] = run;
        run += v;
    }
    in_deg[bin] = run;
    norm_dst[bin] = rsqrtf(fmaxf((float)run, 1.0f));
    int tot = 0;
#pragma unroll
    for (int q = 0; q < Q; ++q) tot += qtot_s[(size_t)q * n + bin];
    norm_src[bin] = rsqrtf(fmaxf((float)tot, 1.0f));
}

// ---------------- exclusive scan of in_deg -> row_start; zero agg cursors ----------------
__global__ __launch_bounds__(1024) void scan_kernel(const int* __restrict__ in_deg, int* __restrict__ row_start,
                                                    int* __restrict__ cursors, int n) {
    __shared__ int buf[NBINS_MAX];
    __shared__ int part[1024];
    int t = threadIdx.x;
    if (t < 16) cursors[t] = 0;
    for (int i = t; i < n; i += 1024) buf[i] = in_deg[i];
    __syncthreads();
    int ipt = (n + 1023) / 1024;
    int lo = min(t * ipt, n), hi = min(lo + ipt, n);
    int s = 0;
    for (int i = lo; i < hi; ++i) s += buf[i];
    part[t] = s;
    __syncthreads();
    for (int off = 1; off < 1024; off <<= 1) {
        int v = 0;
        if (t >= off) v = part[t - off];
        __syncthreads();
        if (t >= off) part[t] += v;
        __syncthreads();
    }
    int run = part[t] - s;
    for (int i = lo; i < hi; ++i) {
        int v = buf[i];
        buf[i] = run;
        run += v;
    }
    __syncthreads();
    for (int i = t; i < n; i += 1024) row_start[i] = buf[i];
    if (t == 0) row_start[n] = part[1023];
}

// ---------------- CSR fill: LDS cursor pre-seeded with absolute slot base ----------------
// Record weight = ew[e] * norm_src[src[e]]  (layer-invariant; folds the src-norm).
__global__ __launch_bounds__(256) void fill_kernel(const int* __restrict__ src, const int* __restrict__ dst,
                                                   const float* __restrict__ ew, const float* __restrict__ ns,
                                                   const int* __restrict__ row_start, const int* __restrict__ qbase,
                                                   const unsigned short* __restrict__ pd,
                                                   int2* __restrict__ sorted, int E, int n) {
    __shared__ int cursor[NBINS_MAX];
    int b = blockIdx.x, t = threadIdx.x;
    int q = b / BQ;
    int chunk = (E + NB - 1) / NB;
    int e0 = b * chunk, e1 = min(e0 + chunk, E);
    for (int i = t; i < n; i += 256)
        cursor[i] = row_start[i] + qbase[(size_t)q * n + i] + (int)pd[(size_t)b * n + i];
    __syncthreads();
    for (int e = e0 + t; e < e1; e += 256) {
        int d = dst[e];
        int slot = atomicAdd(&cursor[d], 1);
        int s = src[e];
        int2 rec;
        rec.x = s;
        rec.y = __float_as_int(ew[e] * ns[s]);
        sorted[slot] = rec;
    }
}

// ---------------- XCD-aware dynamic aggregation ----------------
// 8 partitions: p>>2 = feature chunk (64 floats), p&3 = node quad.
// Each block reads its actual XCD id (HW_REG_XCC_ID) and pulls groups for
// its own partition from a global cursor; steals from others when empty
// (correctness never depends on the id). Per-XCD hot x-slice = 2.56 MB
// -> per-XCD-L2-resident. One wave per (node, chunk): 256B coalesced gathers.
__global__ __launch_bounds__(256) void agg_kernel(const float* __restrict__ h, const int* __restrict__ row_start,
                                                  const int2* __restrict__ sorted, float* __restrict__ out,
                                                  int* __restrict__ cursors, int n, int qn, int gpp) {
    __shared__ int s_g;
    int wave = threadIdx.x >> 6;
    int lane = threadIdx.x & 63;
    unsigned xcc = __builtin_amdgcn_s_getreg(XCC_ID_IMM) & 7u;
#pragma unroll 1
    for (int pi = 0; pi < 8; ++pi) {
        int p = (int)((xcc + (unsigned)pi) & 7u);
        int chunk = p >> 2;
        int quad  = p & 3;
        int hiN   = min((quad + 1) * qn, n);
        const float* hc = h + chunk * 64 + lane;
        for (;;) {
            if (threadIdx.x == 0) s_g = atomicAdd(&cursors[p], 1);
            __syncthreads();
            int g = s_g;
            __syncthreads();
            if (g >= gpp) break;
            int node = quad * qn + g * 4 + wave;
            if (node < hiN) {
                int beg = row_start[node];
                int end = row_start[node + 1];
                float acc = 0.f;
                int s = beg;
                if (s < end && (s & 1)) {   // peel to even -> 16B-aligned int4 record loads
                    int2 rr = sorted[s];
                    acc = fmaf(__int_as_float(rr.y), hc[rr.x << 7], acc);
                    ++s;
                }
                for (; s + 8 <= end; s += 8) {   // 8 independent 256B gathers in flight
                    int4 p0 = *(const int4*)(sorted + s);
                    int4 p1 = *(const int4*)(sorted + s + 2);
                    int4 p2 = *(const int4*)(sorted + s + 4);
                    int4 p3 = *(const int4*)(sorted + s + 6);
                    float x0 = hc[p0.x << 7];
                    float x1 = hc[p0.z << 7];
                    float x2 = hc[p1.x << 7];
                    float x3 = hc[p1.z << 7];
                    float x4 = hc[p2.x << 7];
                    float x5 = hc[p2.z << 7];
                    float x6 = hc[p3.x << 7];
                    float x7 = hc[p3.z << 7];
                    acc = fmaf(__int_as_float(p0.y), x0, acc);
                    acc = fmaf(__int_as_float(p0.w), x1, acc);
                    acc = fmaf(__int_as_float(p1.y), x2, acc);
                    acc = fmaf(__int_as_float(p1.w), x3, acc);
                    acc = fmaf(__int_as_float(p2.y), x4, acc);
                    acc = fmaf(__int_as_float(p2.w), x5, acc);
                    acc = fmaf(__int_as_float(p3.y), x6, acc);
                    acc = fmaf(__int_as_float(p3.w), x7, acc);
                }
                for (; s + 2 <= end; s += 2) {
                    int4 pp = *(const int4*)(sorted + s);
                    acc = fmaf(__int_as_float(pp.y), hc[pp.x << 7], acc);
                    acc = fmaf(__int_as_float(pp.w), hc[pp.z << 7], acc);
                }
                if (s < end) {
                    int2 rr = sorted[s];
                    acc = fmaf(__int_as_float(rr.y), hc[rr.x << 7], acc);
                }
                out[((size_t)node << 7) + chunk * 64 + lane] = acc;
            }
        }
    }
}

// ---------------- GEMM + epilogue: out = relu((A@W)*norm_dst[:,None] + b) ----------------
__global__ __launch_bounds__(256) void gemm_kernel(const float* __restrict__ A, const float* __restrict__ W,
                                                   const float* __restrict__ bias, const float* __restrict__ norm_dst,
                                                   float* __restrict__ out, int n) {
    __shared__ float sA[TROWS * 132];
    int tid = threadIdx.x;
    int row0 = blockIdx.x * TROWS;
    for (int i = tid; i < TROWS * 32; i += 256) {
        int r = i >> 5;
        int q = i & 31;
        int rr = row0 + r;
        float4 v = make_float4(0.f, 0.f, 0.f, 0.f);
        if (rr < n) v = *(const float4*)(A + (size_t)rr * D + q * 4);
        *(float4*)(&sA[r * 132 + q * 4]) = v;
    }
    __syncthreads();
    int ty = tid >> 4;
    int tx = tid & 15;
    int c0 = tx * 8;
    float acc[8];
#pragma unroll
    for (int j = 0; j < 8; ++j) acc[j] = 0.f;
    const float* sa = &sA[ty * 132];
#pragma unroll 4
    for (int k = 0; k < D; ++k) {
        float a = sa[k];
        float4 w0 = *(const float4*)(W + k * D + c0);
        float4 w1 = *(const float4*)(W + k * D + c0 + 4);
        acc[0] = fmaf(a, w0.x, acc[0]);
        acc[1] = fmaf(a, w0.y, acc[1]);
        acc[2] = fmaf(a, w0.z, acc[2]);
        acc[3] = fmaf(a, w0.w, acc[3]);
        acc[4] = fmaf(a, w1.x, acc[4]);
        acc[5] = fmaf(a, w1.y, acc[5]);
        acc[6] = fmaf(a, w1.z, acc[6]);
        acc[7] = fmaf(a, w1.w, acc[7]);
    }
    int r = row0 + ty;
    if (r < n) {
        float nd = norm_dst[r];
        float4 o0, o1;
        o0.x = fmaxf(fmaf(acc[0], nd, bias[c0 + 0]), 0.f);
        o0.y = fmaxf(fmaf(acc[1], nd, bias[c0 + 1]), 0.f);
        o0.z = fmaxf(fmaf(acc[2], nd, bias[c0 + 2]), 0.f);
        o0.w = fmaxf(fmaf(acc[3], nd, bias[c0 + 3]), 0.f);
        o1.x = fmaxf(fmaf(acc[4], nd, bias[c0 + 4]), 0.f);
        o1.y = fmaxf(fmaf(acc[5], nd, bias[c0 + 5]), 0.f);
        o1.z = fmaxf(fmaf(acc[6], nd, bias[c0 + 6]), 0.f);
        o1.w = fmaxf(fmaf(acc[7], nd, bias[c0 + 7]), 0.f);
        *(float4*)(out + (size_t)r * D + c0) = o0;
        *(float4*)(out + (size_t)r * D + c0 + 4) = o1;
    }
}

extern "C" void kernel_launch(void* const* d_in, const int* in_sizes, int n_in,
                              void* d_out, int out_size, void* d_ws, size_t ws_size,
                              hipStream_t stream) {
    const float* x  = (const float*)d_in[0];
    const float* ew = (const float*)d_in[1];
    const float* W0 = (const float*)d_in[2];
    const float* b0 = (const float*)d_in[3];
    const float* W1 = (const float*)d_in[4];
    const float* b1 = (const float*)d_in[5];
    const int* src  = (const int*)d_in[6];
    const int* dst  = (const int*)d_in[7];
    float* out = (float*)d_out;

    int n = in_sizes[0] / D;   // 10000
    int E = in_sizes[6];       // 640000
    if (n <= 0 || E <= 0) return;

    char* ws = (char*)d_ws;
    size_t off = 0;
    auto alloc = [&](size_t bytes) -> void* {
        void* p = ws + off;
        off = (off + bytes + 255) & ~(size_t)255;
        return p;
    };
    int* row_start  = (int*)alloc(((size_t)n + 1) * 4);
    int* in_deg     = (int*)alloc((size_t)n * 4);
    float* norm_src = (float*)alloc((size_t)n * 4);
    float* norm_dst = (float*)alloc((size_t)n * 4);
    int* cursors    = (int*)alloc(16 * 4);              // 8 per agg launch
    int* qtot_d     = (int*)alloc((size_t)Q * n * 4);   // becomes qbase in finalize
    int* qtot_s     = (int*)alloc((size_t)Q * n * 4);
    size_t sorted_bytes = (size_t)E * 8;
    size_t ps_bytes = (size_t)NB * n * 2;
    int2* sorted    = (int2*)alloc(sorted_bytes > ps_bytes ? sorted_bytes : ps_bytes);
    float* B1       = (float*)alloc((size_t)n * D * 4);   // agg output
    float* B2       = (float*)alloc((size_t)n * D * 4);   // h1
    // pd (NB*n ushorts = 5.12 MB) aliases B1 (5.12 MB); consumed by fill before agg writes B1.
    unsigned short* pd = (unsigned short*)B1;
    // ps (NB*n ushorts) aliases sorted; consumed by colscan before fill writes sorted.
    unsigned short* ps = (unsigned short*)sorted;

    int nb = (n + 255) / 256;
    int qn  = (n + 3) / 4;          // nodes per quad
    int gpp = (qn + 3) / 4;         // groups (of 4 nodes) per partition
    int ab  = 2048;                 // dynamic blocks: 8/CU, full wave occupancy
    int gb = (n + TROWS - 1) / TROWS;

    hist_kernel<<<NB, 256, 0, stream>>>(src, dst, pd, ps, E, n);
    colscan_kernel<<<dim3(nb, Q), 256, 0, stream>>>(pd, ps, qtot_d, qtot_s, n);
    finalize_kernel<<<nb, 256, 0, stream>>>(qtot_d, qtot_s, in_deg, norm_src, norm_dst, n);
    scan_kernel<<<1, 1024, 0, stream>>>(in_deg, row_start, cursors, n);
    fill_kernel<<<NB, 256, 0, stream>>>(src, dst, ew, norm_src, row_start, qtot_d, pd, sorted, E, n);

    // layer 1: agg x (norm_src folded in records) -> B1, gemm -> B2
    agg_kernel<<<ab, 256, 0, stream>>>(x, row_start, sorted, B1, cursors, n, qn, gpp);
    gemm_kernel<<<gb, 256, 0, stream>>>(B1, W0, b0, norm_dst, B2, n);
    // layer 2: agg B2 -> B1, gemm -> out
    agg_kernel<<<ab, 256, 0, stream>>>(B2, row_start, sorted, B1, cursors + 8, n, qn, gpp);
    gemm_kernel<<<gb, 256, 0, stream>>>(B1, W1, b1, norm_dst, out, n);
}

// Round 9
// 266.387 us; speedup vs baseline: 2.5197x; 2.5197x over previous
//
#include <hip/hip_runtime.h>

#define D 128
#define NB 256          // counting-sort chunks (one block each)
#define Q 16            // sections for the b-dimension scan (prefix fits ushort)
#define BQ (NB / Q)     // blocks per section = 16
#define NBINS_MAX 10016 // max nodes supported by LDS histogram (~40 KB)
#define TROWS 16
#define CURS 32         // cursor stride in ints (128 B -> one cache line per partition)
#define SPAN 2          // groups (of 4 nodes) per cursor pull
// HW_REG_XCC_ID (id=20, offset=0, size=32) -> s_getreg imm encoding
#define XCC_ID_IMM (20 | (31 << 11))

// ---------------- fused per-chunk LDS histograms of dst and src ----------------
__global__ __launch_bounds__(256) void hist_kernel(const int* __restrict__ src, const int* __restrict__ dst,
                                                   unsigned short* __restrict__ pd, unsigned short* __restrict__ ps,
                                                   int E, int n) {
    __shared__ int hd[NBINS_MAX];
    __shared__ int hs[NBINS_MAX];
    int b = blockIdx.x, t = threadIdx.x;
    int chunk = (E + NB - 1) / NB;
    int e0 = b * chunk, e1 = min(e0 + chunk, E);
    for (int i = t; i < n; i += 256) { hd[i] = 0; hs[i] = 0; }
    __syncthreads();
    for (int e = e0 + t; e < e1; e += 256) {
        atomicAdd(&hd[dst[e]], 1);
        atomicAdd(&hs[src[e]], 1);
    }
    __syncthreads();
    for (int i = t; i < n; i += 256) {
        pd[(size_t)b * n + i] = (unsigned short)hd[i];
        ps[(size_t)b * n + i] = (unsigned short)hs[i];
    }
}

// ---------------- within-section exclusive scan of pd along b (in place, ushort) ----------------
__global__ __launch_bounds__(256) void colscan_kernel(unsigned short* __restrict__ pd,
                                                      const unsigned short* __restrict__ ps,
                                                      int* __restrict__ qtot_d, int* __restrict__ qtot_s, int n) {
    int bin = blockIdx.x * 256 + threadIdx.x;
    int q = blockIdx.y;
    if (bin >= n) return;
    int b0 = q * BQ;
    int run = 0, ssum = 0;
#pragma unroll
    for (int j = 0; j < BQ; ++j) {
        size_t idx = (size_t)(b0 + j) * n + bin;
        int v = (int)pd[idx];
        pd[idx] = (unsigned short)run;   // max 16*2500 = 40000 < 65536
        run += v;
        ssum += (int)ps[idx];
    }
    qtot_d[(size_t)q * n + bin] = run;
    qtot_s[(size_t)q * n + bin] = ssum;
}

// ---------------- per-bin: scan section totals -> bases; degrees -> norms ----------------
__global__ __launch_bounds__(256) void finalize_kernel(int* __restrict__ qtot_d /* becomes qbase */,
                                                       const int* __restrict__ qtot_s,
                                                       int* __restrict__ in_deg,
                                                       float* __restrict__ norm_src, float* __restrict__ norm_dst,
                                                       int n) {
    int bin = blockIdx.x * 256 + threadIdx.x;
    if (bin >= n) return;
    int run = 0;
#pragma unroll
    for (int q = 0; q < Q; ++q) {
        size_t i = (size_t)q * n + bin;
        int v = qtot_d[i];
        qtot_d[i] = run;
        run += v;
    }
    in_deg[bin] = run;
    norm_dst[bin] = rsqrtf(fmaxf((float)run, 1.0f));
    int tot = 0;
#pragma unroll
    for (int q = 0; q < Q; ++q) tot += qtot_s[(size_t)q * n + bin];
    norm_src[bin] = rsqrtf(fmaxf((float)tot, 1.0f));
}

// ---------------- exclusive scan of in_deg -> row_start; zero agg cursors ----------------
__global__ __launch_bounds__(1024) void scan_kernel(const int* __restrict__ in_deg, int* __restrict__ row_start,
                                                    int* __restrict__ cursors, int n) {
    __shared__ int buf[NBINS_MAX];
    __shared__ int part[1024];
    int t = threadIdx.x;
    if (t < 16 * CURS) cursors[t] = 0;
    for (int i = t; i < n; i += 1024) buf[i] = in_deg[i];
    __syncthreads();
    int ipt = (n + 1023) / 1024;
    int lo = min(t * ipt, n), hi = min(lo + ipt, n);
    int s = 0;
    for (int i = lo; i < hi; ++i) s += buf[i];
    part[t] = s;
    __syncthreads();
    for (int off = 1; off < 1024; off <<= 1) {
        int v = 0;
        if (t >= off) v = part[t - off];
        __syncthreads();
        if (t >= off) part[t] += v;
        __syncthreads();
    }
    int run = part[t] - s;
    for (int i = lo; i < hi; ++i) {
        int v = buf[i];
        buf[i] = run;
        run += v;
    }
    __syncthreads();
    for (int i = t; i < n; i += 1024) row_start[i] = buf[i];
    if (t == 0) row_start[n] = part[1023];
}

// ---------------- CSR fill: LDS cursor pre-seeded with absolute slot base ----------------
// Record weight = ew[e] * norm_src[src[e]]  (layer-invariant; folds the src-norm).
__global__ __launch_bounds__(256) void fill_kernel(const int* __restrict__ src, const int* __restrict__ dst,
                                                   const float* __restrict__ ew, const float* __restrict__ ns,
                                                   const int* __restrict__ row_start, const int* __restrict__ qbase,
                                                   const unsigned short* __restrict__ pd,
                                                   int2* __restrict__ sorted, int E, int n) {
    __shared__ int cursor[NBINS_MAX];
    int b = blockIdx.x, t = threadIdx.x;
    int q = b / BQ;
    int chunk = (E + NB - 1) / NB;
    int e0 = b * chunk, e1 = min(e0 + chunk, E);
    for (int i = t; i < n; i += 256)
        cursor[i] = row_start[i] + qbase[(size_t)q * n + i] + (int)pd[(size_t)b * n + i];
    __syncthreads();
    for (int e = e0 + t; e < e1; e += 256) {
        int d = dst[e];
        int slot = atomicAdd(&cursor[d], 1);
        int s = src[e];
        int2 rec;
        rec.x = s;
        rec.y = __float_as_int(ew[e] * ns[s]);
        sorted[slot] = rec;
    }
}

// ---------------- XCD-aware aggregation, span-pull scheduling ----------------
// 8 partitions: p>>2 = feature chunk (64 floats), p&3 = node quad.
// Block reads its XCD id and drains its own partition's cursor (one 128B line
// per partition -> atomics stay in the home XCD's L2), SPAN groups per pull.
// Stealing from other partitions (correctness if id/mapping ever lies) is
// gated by a plain pre-load: stale reads are monotonically <= actual, so they
// can only cause a redundant-but-safe atomic, never a missed node.
__global__ __launch_bounds__(256) void agg_kernel(const float* __restrict__ h, const int* __restrict__ row_start,
                                                  const int2* __restrict__ sorted, float* __restrict__ out,
                                                  int* __restrict__ cursors, int n, int qn, int nspans) {
    __shared__ int s_g;
    int wave = threadIdx.x >> 6;
    int lane = threadIdx.x & 63;
    unsigned xcc = __builtin_amdgcn_s_getreg(XCC_ID_IMM) & 7u;
#pragma unroll 1
    for (int pi = 0; pi < 8; ++pi) {
        int p = (int)((xcc + (unsigned)pi) & 7u);
        int chunk = p >> 2;
        int quad  = p & 3;
        int hiN   = min((quad + 1) * qn, n);
        const float* hc = h + chunk * 64 + lane;
        int* curp = cursors + p * CURS;
        for (;;) {
            if (pi > 0) {   // cheap pre-check before stealing
                if (threadIdx.x == 0) s_g = *(volatile int*)curp;
                __syncthreads();
                int seen = s_g;
                __syncthreads();
                if (seen >= nspans) break;
            }
            if (threadIdx.x == 0) s_g = atomicAdd(curp, 1);
            __syncthreads();
            int span = s_g;
            __syncthreads();
            if (span >= nspans) break;
#pragma unroll 1
            for (int j = 0; j < SPAN; ++j) {
                int node = quad * qn + (span * SPAN + j) * 4 + wave;
                if (node >= hiN) continue;
                int beg = row_start[node];
                int end = row_start[node + 1];
                float acc = 0.f;
                int s = beg;
                if (s < end && (s & 1)) {   // peel to even -> 16B-aligned int4 record loads
                    int2 rr = sorted[s];
                    acc = fmaf(__int_as_float(rr.y), hc[rr.x << 7], acc);
                    ++s;
                }
                for (; s + 8 <= end; s += 8) {   // 8 independent 256B gathers in flight
                    int4 p0 = *(const int4*)(sorted + s);
                    int4 p1 = *(const int4*)(sorted + s + 2);
                    int4 p2 = *(const int4*)(sorted + s + 4);
                    int4 p3 = *(const int4*)(sorted + s + 6);
                    float x0 = hc[p0.x << 7];
                    float x1 = hc[p0.z << 7];
                    float x2 = hc[p1.x << 7];
                    float x3 = hc[p1.z << 7];
                    float x4 = hc[p2.x << 7];
                    float x5 = hc[p2.z << 7];
                    float x6 = hc[p3.x << 7];
                    float x7 = hc[p3.z << 7];
                    acc = fmaf(__int_as_float(p0.y), x0, acc);
                    acc = fmaf(__int_as_float(p0.w), x1, acc);
                    acc = fmaf(__int_as_float(p1.y), x2, acc);
                    acc = fmaf(__int_as_float(p1.w), x3, acc);
                    acc = fmaf(__int_as_float(p2.y), x4, acc);
                    acc = fmaf(__int_as_float(p2.w), x5, acc);
                    acc = fmaf(__int_as_float(p3.y), x6, acc);
                    acc = fmaf(__int_as_float(p3.w), x7, acc);
                }
                for (; s + 2 <= end; s += 2) {
                    int4 pp = *(const int4*)(sorted + s);
                    acc = fmaf(__int_as_float(pp.y), hc[pp.x << 7], acc);
                    acc = fmaf(__int_as_float(pp.w), hc[pp.z << 7], acc);
                }
                if (s < end) {
                    int2 rr = sorted[s];
                    acc = fmaf(__int_as_float(rr.y), hc[rr.x << 7], acc);
                }
                out[((size_t)node << 7) + chunk * 64 + lane] = acc;
            }
        }
    }
}

// ---------------- GEMM + epilogue: out = relu((A@W)*norm_dst[:,None] + b) ----------------
__global__ __launch_bounds__(256) void gemm_kernel(const float* __restrict__ A, const float* __restrict__ W,
                                                   const float* __restrict__ bias, const float* __restrict__ norm_dst,
                                                   float* __restrict__ out, int n) {
    __shared__ float sA[TROWS * 132];
    int tid = threadIdx.x;
    int row0 = blockIdx.x * TROWS;
    for (int i = tid; i < TROWS * 32; i += 256) {
        int r = i >> 5;
        int q = i & 31;
        int rr = row0 + r;
        float4 v = make_float4(0.f, 0.f, 0.f, 0.f);
        if (rr < n) v = *(const float4*)(A + (size_t)rr * D + q * 4);
        *(float4*)(&sA[r * 132 + q * 4]) = v;
    }
    __syncthreads();
    int ty = tid >> 4;
    int tx = tid & 15;
    int c0 = tx * 8;
    float acc[8];
#pragma unroll
    for (int j = 0; j < 8; ++j) acc[j] = 0.f;
    const float* sa = &sA[ty * 132];
#pragma unroll 4
    for (int k = 0; k < D; ++k) {
        float a = sa[k];
        float4 w0 = *(const float4*)(W + k * D + c0);
        float4 w1 = *(const float4*)(W + k * D + c0 + 4);
        acc[0] = fmaf(a, w0.x, acc[0]);
        acc[1] = fmaf(a, w0.y, acc[1]);
        acc[2] = fmaf(a, w0.z, acc[2]);
        acc[3] = fmaf(a, w0.w, acc[3]);
        acc[4] = fmaf(a, w1.x, acc[4]);
        acc[5] = fmaf(a, w1.y, acc[5]);
        acc[6] = fmaf(a, w1.z, acc[6]);
        acc[7] = fmaf(a, w1.w, acc[7]);
    }
    int r = row0 + ty;
    if (r < n) {
        float nd = norm_dst[r];
        float4 o0, o1;
        o0.x = fmaxf(fmaf(acc[0], nd, bias[c0 + 0]), 0.f);
        o0.y = fmaxf(fmaf(acc[1], nd, bias[c0 + 1]), 0.f);
        o0.z = fmaxf(fmaf(acc[2], nd, bias[c0 + 2]), 0.f);
        o0.w = fmaxf(fmaf(acc[3], nd, bias[c0 + 3]), 0.f);
        o1.x = fmaxf(fmaf(acc[4], nd, bias[c0 + 4]), 0.f);
        o1.y = fmaxf(fmaf(acc[5], nd, bias[c0 + 5]), 0.f);
        o1.z = fmaxf(fmaf(acc[6], nd, bias[c0 + 6]), 0.f);
        o1.w = fmaxf(fmaf(acc[7], nd, bias[c0 + 7]), 0.f);
        *(float4*)(out + (size_t)r * D + c0) = o0;
        *(float4*)(out + (size_t)r * D + c0 + 4) = o1;
    }
}

extern "C" void kernel_launch(void* const* d_in, const int* in_sizes, int n_in,
                              void* d_out, int out_size, void* d_ws, size_t ws_size,
                              hipStream_t stream) {
    const float* x  = (const float*)d_in[0];
    const float* ew = (const float*)d_in[1];
    const float* W0 = (const float*)d_in[2];
    const float* b0 = (const float*)d_in[3];
    const float* W1 = (const float*)d_in[4];
    const float* b1 = (const float*)d_in[5];
    const int* src  = (const int*)d_in[6];
    const int* dst  = (const int*)d_in[7];
    float* out = (float*)d_out;

    int n = in_sizes[0] / D;   // 10000
    int E = in_sizes[6];       // 640000
    if (n <= 0 || E <= 0) return;

    char* ws = (char*)d_ws;
    size_t off = 0;
    auto alloc = [&](size_t bytes) -> void* {
        void* p = ws + off;
        off = (off + bytes + 255) & ~(size_t)255;
        return p;
    };
    int* row_start  = (int*)alloc(((size_t)n + 1) * 4);
    int* in_deg     = (int*)alloc((size_t)n * 4);
    float* norm_src = (float*)alloc((size_t)n * 4);
    float* norm_dst = (float*)alloc((size_t)n * 4);
    int* cursors    = (int*)alloc(16 * CURS * 4);       // 8 per agg launch, 128B apart
    int* qtot_d     = (int*)alloc((size_t)Q * n * 4);   // becomes qbase in finalize
    int* qtot_s     = (int*)alloc((size_t)Q * n * 4);
    size_t sorted_bytes = (size_t)E * 8;
    size_t ps_bytes = (size_t)NB * n * 2;
    int2* sorted    = (int2*)alloc(sorted_bytes > ps_bytes ? sorted_bytes : ps_bytes);
    float* B1       = (float*)alloc((size_t)n * D * 4);   // agg output
    float* B2       = (float*)alloc((size_t)n * D * 4);   // h1
    // pd (NB*n ushorts = 5.12 MB) aliases B1 (5.12 MB); consumed by fill before agg writes B1.
    unsigned short* pd = (unsigned short*)B1;
    // ps (NB*n ushorts) aliases sorted; consumed by colscan before fill writes sorted.
    unsigned short* ps = (unsigned short*)sorted;

    int nb = (n + 255) / 256;
    int qn     = (n + 3) / 4;              // nodes per quad
    int gpp    = (qn + 3) / 4;             // groups (of 4 nodes) per partition
    int nspans = (gpp + SPAN - 1) / SPAN;  // cursor pulls per partition
    int ab     = 2048;                     // 8 blocks/CU
    int gb = (n + TROWS - 1) / TROWS;

    hist_kernel<<<NB, 256, 0, stream>>>(src, dst, pd, ps, E, n);
    colscan_kernel<<<dim3(nb, Q), 256, 0, stream>>>(pd, ps, qtot_d, qtot_s, n);
    finalize_kernel<<<nb, 256, 0, stream>>>(qtot_d, qtot_s, in_deg, norm_src, norm_dst, n);
    scan_kernel<<<1, 1024, 0, stream>>>(in_deg, row_start, cursors, n);
    fill_kernel<<<NB, 256, 0, stream>>>(src, dst, ew, norm_src, row_start, qtot_d, pd, sorted, E, n);

    // layer 1: agg x (norm_src folded in records) -> B1, gemm -> B2
    agg_kernel<<<ab, 256, 0, stream>>>(x, row_start, sorted, B1, cursors, n, qn, nspans);
    gemm_kernel<<<gb, 256, 0, stream>>>(B1, W0, b0, norm_dst, B2, n);
    // layer 2: agg B2 -> B1, gemm -> out
    agg_kernel<<<ab, 256, 0, stream>>>(B2, row_start, sorted, B1, cursors + 8 * CURS, n, qn, nspans);
    gemm_kernel<<<gb, 256, 0, stream>>>(B1, W1, b1, norm_dst, out, n);
}

// Round 11
// 243.444 us; speedup vs baseline: 2.7572x; 1.0942x over previous
//
#include <hip/hip_runtime.h>

#define D 128
#define NB 256          // counting-sort chunks (one block each)
#define Q 16            // sections for the b-dimension scan (prefix fits ushort)
#define BQ (NB / Q)     // blocks per section = 16
#define NBINS_MAX 10016 // max nodes supported by LDS histogram (~40 KB)
#define TROWS 16

typedef int v4i __attribute__((ext_vector_type(4)));   // clang vector: OK for nontemporal builtins

// ---------------- fused per-chunk LDS histograms of dst and src ----------------
__global__ __launch_bounds__(256) void hist_kernel(const int* __restrict__ src, const int* __restrict__ dst,
                                                   unsigned short* __restrict__ pd, unsigned short* __restrict__ ps,
                                                   int E, int n) {
    __shared__ int hd[NBINS_MAX];
    __shared__ int hs[NBINS_MAX];
    int b = blockIdx.x, t = threadIdx.x;
    int chunk = (E + NB - 1) / NB;
    int e0 = b * chunk, e1 = min(e0 + chunk, E);
    for (int i = t; i < n; i += 256) { hd[i] = 0; hs[i] = 0; }
    __syncthreads();
    for (int e = e0 + t; e < e1; e += 256) {
        atomicAdd(&hd[dst[e]], 1);
        atomicAdd(&hs[src[e]], 1);
    }
    __syncthreads();
    for (int i = t; i < n; i += 256) {
        pd[(size_t)b * n + i] = (unsigned short)hd[i];
        ps[(size_t)b * n + i] = (unsigned short)hs[i];
    }
}

// ---------------- within-section exclusive scan of pd along b (in place, ushort) ----------------
__global__ __launch_bounds__(256) void colscan_kernel(unsigned short* __restrict__ pd,
                                                      const unsigned short* __restrict__ ps,
                                                      int* __restrict__ qtot_d, int* __restrict__ qtot_s, int n) {
    int bin = blockIdx.x * 256 + threadIdx.x;
    int q = blockIdx.y;
    if (bin >= n) return;
    int b0 = q * BQ;
    int run = 0, ssum = 0;
#pragma unroll
    for (int j = 0; j < BQ; ++j) {
        size_t idx = (size_t)(b0 + j) * n + bin;
        int v = (int)pd[idx];
        pd[idx] = (unsigned short)run;   // max 16*2500 = 40000 < 65536
        run += v;
        ssum += (int)ps[idx];
    }
    qtot_d[(size_t)q * n + bin] = run;
    qtot_s[(size_t)q * n + bin] = ssum;
}

// ---------------- per-bin: scan section totals -> bases; degrees -> norms ----------------
__global__ __launch_bounds__(256) void finalize_kernel(int* __restrict__ qtot_d /* becomes qbase */,
                                                       const int* __restrict__ qtot_s,
                                                       int* __restrict__ in_deg,
                                                       float* __restrict__ norm_src, float* __restrict__ norm_dst,
                                                       int n) {
    int bin = blockIdx.x * 256 + threadIdx.x;
    if (bin >= n) return;
    int run = 0;
#pragma unroll
    for (int q = 0; q < Q; ++q) {
        size_t i = (size_t)q * n + bin;
        int v = qtot_d[i];
        qtot_d[i] = run;
        run += v;
    }
    in_deg[bin] = run;
    norm_dst[bin] = rsqrtf(fmaxf((float)run, 1.0f));
    int tot = 0;
#pragma unroll
    for (int q = 0; q < Q; ++q) tot += qtot_s[(size_t)q * n + bin];
    norm_src[bin] = rsqrtf(fmaxf((float)tot, 1.0f));
}

// ---------------- exclusive scan of in_deg -> row_start (single block, LDS-staged) ----------------
__global__ __launch_bounds__(1024) void scan_kernel(const int* __restrict__ in_deg, int* __restrict__ row_start, int n) {
    __shared__ int buf[NBINS_MAX];
    __shared__ int part[1024];
    int t = threadIdx.x;
    for (int i = t; i < n; i += 1024) buf[i] = in_deg[i];
    __syncthreads();
    int ipt = (n + 1023) / 1024;
    int lo = min(t * ipt, n), hi = min(lo + ipt, n);
    int s = 0;
    for (int i = lo; i < hi; ++i) s += buf[i];
    part[t] = s;
    __syncthreads();
    for (int off = 1; off < 1024; off <<= 1) {
        int v = 0;
        if (t >= off) v = part[t - off];
        __syncthreads();
        if (t >= off) part[t] += v;
        __syncthreads();
    }
    int run = part[t] - s;
    for (int i = lo; i < hi; ++i) {
        int v = buf[i];
        buf[i] = run;
        run += v;
    }
    __syncthreads();
    for (int i = t; i < n; i += 1024) row_start[i] = buf[i];
    if (t == 0) row_start[n] = part[1023];
}

// ---------------- CSR fill: LDS cursor pre-seeded with absolute slot base ----------------
// Record weight = ew[e] * norm_src[src[e]]  (layer-invariant; folds the src-norm).
__global__ __launch_bounds__(256) void fill_kernel(const int* __restrict__ src, const int* __restrict__ dst,
                                                   const float* __restrict__ ew, const float* __restrict__ ns,
                                                   const int* __restrict__ row_start, const int* __restrict__ qbase,
                                                   const unsigned short* __restrict__ pd,
                                                   int2* __restrict__ sorted, int E, int n) {
    __shared__ int cursor[NBINS_MAX];
    int b = blockIdx.x, t = threadIdx.x;
    int q = b / BQ;
    int chunk = (E + NB - 1) / NB;
    int e0 = b * chunk, e1 = min(e0 + chunk, E);
    for (int i = t; i < n; i += 256)
        cursor[i] = row_start[i] + qbase[(size_t)q * n + i] + (int)pd[(size_t)b * n + i];
    __syncthreads();
    for (int e = e0 + t; e < e1; e += 256) {
        int d = dst[e];
        int slot = atomicAdd(&cursor[d], 1);
        int s = src[e];
        int2 rec;
        rec.x = s;
        rec.y = __float_as_int(ew[e] * ns[s]);
        sorted[slot] = rec;
    }
}

// ---------------- time-phased feature-chunk aggregation (static, no atomics) ----------------
// 2*bpc blocks: blocks [0,bpc) do columns [0,64) for all nodes, blocks [bpc,2*bpc)
// do columns [64,128). Dispatch is ~in-order, so the two chunks execute mostly
// sequentially -> instantaneous hot x-slice per XCD ~2.56 MB < 4 MB L2, on every
// XCD, with zero mapping assumptions (mixing only affects speed). One wave per
// (node, chunk): 64 lanes x 1 float = coalesced 256B row gathers. Record stream
// read nontemporally so it doesn't evict the resident x-slice.
__global__ __launch_bounds__(256) void agg_kernel(const float* __restrict__ h, const int* __restrict__ row_start,
                                                  const int2* __restrict__ sorted, float* __restrict__ out,
                                                  int n, int bpc) {
    int b = blockIdx.x;
    int chunk = (b >= bpc) ? 1 : 0;
    int nb = b - chunk * bpc;
    int wave = threadIdx.x >> 6;
    int lane = threadIdx.x & 63;
    int node = nb * 4 + wave;
    if (node >= n) return;
    const float* hc = h + chunk * 64 + lane;
    int beg = row_start[node];
    int end = row_start[node + 1];
    float acc = 0.f;
    int s = beg;
    if (s < end && (s & 1)) {   // peel to even -> 16B-aligned v4i record loads
        int2 rr = sorted[s];
        acc = fmaf(__int_as_float(rr.y), hc[rr.x << 7], acc);
        ++s;
    }
    for (; s + 8 <= end; s += 8) {   // 8 independent 256B gathers in flight
        v4i p0 = __builtin_nontemporal_load((const v4i*)(sorted + s));
        v4i p1 = __builtin_nontemporal_load((const v4i*)(sorted + s + 2));
        v4i p2 = __builtin_nontemporal_load((const v4i*)(sorted + s + 4));
        v4i p3 = __builtin_nontemporal_load((const v4i*)(sorted + s + 6));
        float x0 = hc[p0.x << 7];
        float x1 = hc[p0.z << 7];
        float x2 = hc[p1.x << 7];
        float x3 = hc[p1.z << 7];
        float x4 = hc[p2.x << 7];
        float x5 = hc[p2.z << 7];
        float x6 = hc[p3.x << 7];
        float x7 = hc[p3.z << 7];
        acc = fmaf(__int_as_float(p0.y), x0, acc);
        acc = fmaf(__int_as_float(p0.w), x1, acc);
        acc = fmaf(__int_as_float(p1.y), x2, acc);
        acc = fmaf(__int_as_float(p1.w), x3, acc);
        acc = fmaf(__int_as_float(p2.y), x4, acc);
        acc = fmaf(__int_as_float(p2.w), x5, acc);
        acc = fmaf(__int_as_float(p3.y), x6, acc);
        acc = fmaf(__int_as_float(p3.w), x7, acc);
    }
    for (; s + 2 <= end; s += 2) {
        v4i pp = __builtin_nontemporal_load((const v4i*)(sorted + s));
        acc = fmaf(__int_as_float(pp.y), hc[pp.x << 7], acc);
        acc = fmaf(__int_as_float(pp.w), hc[pp.z << 7], acc);
    }
    if (s < end) {
        int2 rr = sorted[s];
        acc = fmaf(__int_as_float(rr.y), hc[rr.x << 7], acc);
    }
    out[((size_t)node << 7) + chunk * 64 + lane] = acc;
}

// ---------------- GEMM + epilogue: out = relu((A@W)*norm_dst[:,None] + b) ----------------
__global__ __launch_bounds__(256) void gemm_kernel(const float* __restrict__ A, const float* __restrict__ W,
                                                   const float* __restrict__ bias, const float* __restrict__ norm_dst,
                                                   float* __restrict__ out, int n) {
    __shared__ float sA[TROWS * 132];
    int tid = threadIdx.x;
    int row0 = blockIdx.x * TROWS;
    for (int i = tid; i < TROWS * 32; i += 256) {
        int r = i >> 5;
        int q = i & 31;
        int rr = row0 + r;
        float4 v = make_float4(0.f, 0.f, 0.f, 0.f);
        if (rr < n) v = *(const float4*)(A + (size_t)rr * D + q * 4);
        *(float4*)(&sA[r * 132 + q * 4]) = v;
    }
    __syncthreads();
    int ty = tid >> 4;
    int tx = tid & 15;
    int c0 = tx * 8;
    float acc[8];
#pragma unroll
    for (int j = 0; j < 8; ++j) acc[j] = 0.f;
    const float* sa = &sA[ty * 132];
#pragma unroll 4
    for (int k = 0; k < D; ++k) {
        float a = sa[k];
        float4 w0 = *(const float4*)(W + k * D + c0);
        float4 w1 = *(const float4*)(W + k * D + c0 + 4);
        acc[0] = fmaf(a, w0.x, acc[0]);
        acc[1] = fmaf(a, w0.y, acc[1]);
        acc[2] = fmaf(a, w0.z, acc[2]);
        acc[3] = fmaf(a, w0.w, acc[3]);
        acc[4] = fmaf(a, w1.x, acc[4]);
        acc[5] = fmaf(a, w1.y, acc[5]);
        acc[6] = fmaf(a, w1.z, acc[6]);
        acc[7] = fmaf(a, w1.w, acc[7]);
    }
    int r = row0 + ty;
    if (r < n) {
        float nd = norm_dst[r];
        float4 o0, o1;
        o0.x = fmaxf(fmaf(acc[0], nd, bias[c0 + 0]), 0.f);
        o0.y = fmaxf(fmaf(acc[1], nd, bias[c0 + 1]), 0.f);
        o0.z = fmaxf(fmaf(acc[2], nd, bias[c0 + 2]), 0.f);
        o0.w = fmaxf(fmaf(acc[3], nd, bias[c0 + 3]), 0.f);
        o1.x = fmaxf(fmaf(acc[4], nd, bias[c0 + 4]), 0.f);
        o1.y = fmaxf(fmaf(acc[5], nd, bias[c0 + 5]), 0.f);
        o1.z = fmaxf(fmaf(acc[6], nd, bias[c0 + 6]), 0.f);
        o1.w = fmaxf(fmaf(acc[7], nd, bias[c0 + 7]), 0.f);
        *(float4*)(out + (size_t)r * D + c0) = o0;
        *(float4*)(out + (size_t)r * D + c0 + 4) = o1;
    }
}

extern "C" void kernel_launch(void* const* d_in, const int* in_sizes, int n_in,
                              void* d_out, int out_size, void* d_ws, size_t ws_size,
                              hipStream_t stream) {
    const float* x  = (const float*)d_in[0];
    const float* ew = (const float*)d_in[1];
    const float* W0 = (const float*)d_in[2];
    const float* b0 = (const float*)d_in[3];
    const float* W1 = (const float*)d_in[4];
    const float* b1 = (const float*)d_in[5];
    const int* src  = (const int*)d_in[6];
    const int* dst  = (const int*)d_in[7];
    float* out = (float*)d_out;

    int n = in_sizes[0] / D;   // 10000
    int E = in_sizes[6];       // 640000
    if (n <= 0 || E <= 0) return;

    char* ws = (char*)d_ws;
    size_t off = 0;
    auto alloc = [&](size_t bytes) -> void* {
        void* p = ws + off;
        off = (off + bytes + 255) & ~(size_t)255;
        return p;
    };
    int* row_start  = (int*)alloc(((size_t)n + 1) * 4);
    int* in_deg     = (int*)alloc((size_t)n * 4);
    float* norm_src = (float*)alloc((size_t)n * 4);
    float* norm_dst = (float*)alloc((size_t)n * 4);
    int* qtot_d     = (int*)alloc((size_t)Q * n * 4);   // becomes qbase in finalize
    int* qtot_s     = (int*)alloc((size_t)Q * n * 4);
    size_t sorted_bytes = (size_t)E * 8;
    size_t ps_bytes = (size_t)NB * n * 2;
    int2* sorted    = (int2*)alloc(sorted_bytes > ps_bytes ? sorted_bytes : ps_bytes);
    float* B1       = (float*)alloc((size_t)n * D * 4);   // agg output
    float* B2       = (float*)alloc((size_t)n * D * 4);   // h1
    // pd (NB*n ushorts = 5.12 MB) aliases B1 (5.12 MB); consumed by fill before agg writes B1.
    unsigned short* pd = (unsigned short*)B1;
    // ps (NB*n ushorts) aliases sorted; consumed by colscan before fill writes sorted.
    unsigned short* ps = (unsigned short*)sorted;

    int nb  = (n + 255) / 256;
    int bpc = (n + 3) / 4;          // blocks per feature chunk (4 waves per block)
    int ab  = 2 * bpc;              // chunk 0 blocks first, then chunk 1
    int gb  = (n + TROWS - 1) / TROWS;

    hist_kernel<<<NB, 256, 0, stream>>>(src, dst, pd, ps, E, n);
    colscan_kernel<<<dim3(nb, Q), 256, 0, stream>>>(pd, ps, qtot_d, qtot_s, n);
    finalize_kernel<<<nb, 256, 0, stream>>>(qtot_d, qtot_s, in_deg, norm_src, norm_dst, n);
    scan_kernel<<<1, 1024, 0, stream>>>(in_deg, row_start, n);
    fill_kernel<<<NB, 256, 0, stream>>>(src, dst, ew, norm_src, row_start, qtot_d, pd, sorted, E, n);

    // layer 1: agg x (norm_src folded in records) -> B1, gemm -> B2
    agg_kernel<<<ab, 256, 0, stream>>>(x, row_start, sorted, B1, n, bpc);
    gemm_kernel<<<gb, 256, 0, stream>>>(B1, W0, b0, norm_dst, B2, n);
    // layer 2: agg B2 -> B1, gemm -> out
    agg_kernel<<<ab, 256, 0, stream>>>(B2, row_start, sorted, B1, n, bpc);
    gemm_kernel<<<gb, 256, 0, stream>>>(B1, W1, b1, norm_dst, out, n);
}

// Round 12
// 241.640 us; speedup vs baseline: 2.7778x; 1.0075x over previous
//
#include <hip/hip_runtime.h>

#define D 128
#define NB 256          // counting-sort chunks (one block each)
#define Q 16            // sections for the b-dimension scan (prefix fits ushort)
#define BQ (NB / Q)     // blocks per section = 16
#define NBINS_MAX 10016 // max nodes supported by LDS histogram (~40 KB)
#define TROWS 16

typedef int v4i __attribute__((ext_vector_type(4)));   // clang vector: OK for nontemporal builtins

// ---------------- fused per-chunk LDS histograms of dst and src ----------------
__global__ __launch_bounds__(256) void hist_kernel(const int* __restrict__ src, const int* __restrict__ dst,
                                                   unsigned short* __restrict__ pd, unsigned short* __restrict__ ps,
                                                   int E, int n) {
    __shared__ int hd[NBINS_MAX];
    __shared__ int hs[NBINS_MAX];
    int b = blockIdx.x, t = threadIdx.x;
    int chunk = (E + NB - 1) / NB;
    int e0 = b * chunk, e1 = min(e0 + chunk, E);
    for (int i = t; i < n; i += 256) { hd[i] = 0; hs[i] = 0; }
    __syncthreads();
    for (int e = e0 + t; e < e1; e += 256) {
        atomicAdd(&hd[dst[e]], 1);
        atomicAdd(&hs[src[e]], 1);
    }
    __syncthreads();
    for (int i = t; i < n; i += 256) {
        pd[(size_t)b * n + i] = (unsigned short)hd[i];
        ps[(size_t)b * n + i] = (unsigned short)hs[i];
    }
}

// ---------------- within-section exclusive scan of pd along b (in place, ushort) ----------------
__global__ __launch_bounds__(256) void colscan_kernel(unsigned short* __restrict__ pd,
                                                      const unsigned short* __restrict__ ps,
                                                      int* __restrict__ qtot_d, int* __restrict__ qtot_s, int n) {
    int bin = blockIdx.x * 256 + threadIdx.x;
    int q = blockIdx.y;
    if (bin >= n) return;
    int b0 = q * BQ;
    int run = 0, ssum = 0;
#pragma unroll
    for (int j = 0; j < BQ; ++j) {
        size_t idx = (size_t)(b0 + j) * n + bin;
        int v = (int)pd[idx];
        pd[idx] = (unsigned short)run;   // max 16*2500 = 40000 < 65536
        run += v;
        ssum += (int)ps[idx];
    }
    qtot_d[(size_t)q * n + bin] = run;
    qtot_s[(size_t)q * n + bin] = ssum;
}

// ---------------- per-bin: scan section totals -> bases; degrees -> norms ----------------
__global__ __launch_bounds__(256) void finalize_kernel(int* __restrict__ qtot_d /* becomes qbase */,
                                                       const int* __restrict__ qtot_s,
                                                       int* __restrict__ in_deg,
                                                       float* __restrict__ norm_src, float* __restrict__ norm_dst,
                                                       int n) {
    int bin = blockIdx.x * 256 + threadIdx.x;
    if (bin >= n) return;
    int run = 0;
#pragma unroll
    for (int q = 0; q < Q; ++q) {
        size_t i = (size_t)q * n + bin;
        int v = qtot_d[i];
        qtot_d[i] = run;
        run += v;
    }
    in_deg[bin] = run;
    norm_dst[bin] = rsqrtf(fmaxf((float)run, 1.0f));
    int tot = 0;
#pragma unroll
    for (int q = 0; q < Q; ++q) tot += qtot_s[(size_t)q * n + bin];
    norm_src[bin] = rsqrtf(fmaxf((float)tot, 1.0f));
}

// ---------------- exclusive scan of in_deg -> row_start (single block, LDS-staged) ----------------
__global__ __launch_bounds__(1024) void scan_kernel(const int* __restrict__ in_deg, int* __restrict__ row_start, int n) {
    __shared__ int buf[NBINS_MAX];
    __shared__ int part[1024];
    int t = threadIdx.x;
    for (int i = t; i < n; i += 1024) buf[i] = in_deg[i];
    __syncthreads();
    int ipt = (n + 1023) / 1024;
    int lo = min(t * ipt, n), hi = min(lo + ipt, n);
    int s = 0;
    for (int i = lo; i < hi; ++i) s += buf[i];
    part[t] = s;
    __syncthreads();
    for (int off = 1; off < 1024; off <<= 1) {
        int v = 0;
        if (t >= off) v = part[t - off];
        __syncthreads();
        if (t >= off) part[t] += v;
        __syncthreads();
    }
    int run = part[t] - s;
    for (int i = lo; i < hi; ++i) {
        int v = buf[i];
        buf[i] = run;
        run += v;
    }
    __syncthreads();
    for (int i = t; i < n; i += 1024) row_start[i] = buf[i];
    if (t == 0) row_start[n] = part[1023];
}

// ---------------- CSR fill: LDS cursor pre-seeded with absolute slot base ----------------
// Record weight = ew[e] * norm_src[src[e]]  (layer-invariant; folds the src-norm).
__global__ __launch_bounds__(256) void fill_kernel(const int* __restrict__ src, const int* __restrict__ dst,
                                                   const float* __restrict__ ew, const float* __restrict__ ns,
                                                   const int* __restrict__ row_start, const int* __restrict__ qbase,
                                                   const unsigned short* __restrict__ pd,
                                                   int2* __restrict__ sorted, int E, int n) {
    __shared__ int cursor[NBINS_MAX];
    int b = blockIdx.x, t = threadIdx.x;
    int q = b / BQ;
    int chunk = (E + NB - 1) / NB;
    int e0 = b * chunk, e1 = min(e0 + chunk, E);
    for (int i = t; i < n; i += 256)
        cursor[i] = row_start[i] + qbase[(size_t)q * n + i] + (int)pd[(size_t)b * n + i];
    __syncthreads();
    for (int e = e0 + t; e < e1; e += 256) {
        int d = dst[e];
        int slot = atomicAdd(&cursor[d], 1);
        int s = src[e];
        int2 rec;
        rec.x = s;
        rec.y = __float_as_int(ew[e] * ns[s]);
        sorted[slot] = rec;
    }
}

// ---------------- static XCD-partitioned aggregation (R7 structure, best) ----------------
// blockIdx%8 -> partition slot (round-robin dispatch heuristic). Slots 0-3:
// feature chunk [0,64); slots 4-7: chunk [64,128); slot&3 = node quad.
// Per-XCD hot x-slice = 2.56 MB -> L2-resident if mapping holds; wrong mapping
// only costs speed. One wave per (node, chunk): coalesced 256B row gathers.
// Record stream loaded nontemporally to avoid evicting the x-slice.
__global__ __launch_bounds__(256) void agg_kernel(const float* __restrict__ h, const int* __restrict__ row_start,
                                                  const int2* __restrict__ sorted, float* __restrict__ out,
                                                  int n, int qn) {
    int slot  = blockIdx.x & 7;
    int g     = blockIdx.x >> 3;
    int chunk = slot >> 2;         // 0 or 1
    int quad  = slot & 3;          // node quad
    int wave  = threadIdx.x >> 6;
    int lane  = threadIdx.x & 63;
    int node  = quad * qn + g * 4 + wave;
    int hiN   = min((quad + 1) * qn, n);
    if (node >= hiN) return;
    const float* hc = h + chunk * 64 + lane;
    int beg = row_start[node];
    int end = row_start[node + 1];
    float acc = 0.f;
    int s = beg;
    if (s < end && (s & 1)) {   // peel to even -> 16B-aligned v4i record loads
        int2 rr = sorted[s];
        acc = fmaf(__int_as_float(rr.y), hc[rr.x << 7], acc);
        ++s;
    }
    for (; s + 8 <= end; s += 8) {    // 8 independent 256B gathers in flight
        v4i p0 = __builtin_nontemporal_load((const v4i*)(sorted + s));
        v4i p1 = __builtin_nontemporal_load((const v4i*)(sorted + s + 2));
        v4i p2 = __builtin_nontemporal_load((const v4i*)(sorted + s + 4));
        v4i p3 = __builtin_nontemporal_load((const v4i*)(sorted + s + 6));
        float x0 = hc[p0.x << 7];
        float x1 = hc[p0.z << 7];
        float x2 = hc[p1.x << 7];
        float x3 = hc[p1.z << 7];
        float x4 = hc[p2.x << 7];
        float x5 = hc[p2.z << 7];
        float x6 = hc[p3.x << 7];
        float x7 = hc[p3.z << 7];
        acc = fmaf(__int_as_float(p0.y), x0, acc);
        acc = fmaf(__int_as_float(p0.w), x1, acc);
        acc = fmaf(__int_as_float(p1.y), x2, acc);
        acc = fmaf(__int_as_float(p1.w), x3, acc);
        acc = fmaf(__int_as_float(p2.y), x4, acc);
        acc = fmaf(__int_as_float(p2.w), x5, acc);
        acc = fmaf(__int_as_float(p3.y), x6, acc);
        acc = fmaf(__int_as_float(p3.w), x7, acc);
    }
    for (; s + 2 <= end; s += 2) {
        v4i pp = __builtin_nontemporal_load((const v4i*)(sorted + s));
        acc = fmaf(__int_as_float(pp.y), hc[pp.x << 7], acc);
        acc = fmaf(__int_as_float(pp.w), hc[pp.z << 7], acc);
    }
    if (s < end) {
        int2 rr = sorted[s];
        acc = fmaf(__int_as_float(rr.y), hc[rr.x << 7], acc);
    }
    out[((size_t)node << 7) + chunk * 64 + lane] = acc;
}

// ---------------- GEMM + epilogue: out = relu((A@W)*norm_dst[:,None] + b) ----------------
__global__ __launch_bounds__(256) void gemm_kernel(const float* __restrict__ A, const float* __restrict__ W,
                                                   const float* __restrict__ bias, const float* __restrict__ norm_dst,
                                                   float* __restrict__ out, int n) {
    __shared__ float sA[TROWS * 132];
    int tid = threadIdx.x;
    int row0 = blockIdx.x * TROWS;
    for (int i = tid; i < TROWS * 32; i += 256) {
        int r = i >> 5;
        int q = i & 31;
        int rr = row0 + r;
        float4 v = make_float4(0.f, 0.f, 0.f, 0.f);
        if (rr < n) v = *(const float4*)(A + (size_t)rr * D + q * 4);
        *(float4*)(&sA[r * 132 + q * 4]) = v;
    }
    __syncthreads();
    int ty = tid >> 4;
    int tx = tid & 15;
    int c0 = tx * 8;
    float acc[8];
#pragma unroll
    for (int j = 0; j < 8; ++j) acc[j] = 0.f;
    const float* sa = &sA[ty * 132];
#pragma unroll 4
    for (int k = 0; k < D; ++k) {
        float a = sa[k];
        float4 w0 = *(const float4*)(W + k * D + c0);
        float4 w1 = *(const float4*)(W + k * D + c0 + 4);
        acc[0] = fmaf(a, w0.x, acc[0]);
        acc[1] = fmaf(a, w0.y, acc[1]);
        acc[2] = fmaf(a, w0.z, acc[2]);
        acc[3] = fmaf(a, w0.w, acc[3]);
        acc[4] = fmaf(a, w1.x, acc[4]);
        acc[5] = fmaf(a, w1.y, acc[5]);
        acc[6] = fmaf(a, w1.z, acc[6]);
        acc[7] = fmaf(a, w1.w, acc[7]);
    }
    int r = row0 + ty;
    if (r < n) {
        float nd = norm_dst[r];
        float4 o0, o1;
        o0.x = fmaxf(fmaf(acc[0], nd, bias[c0 + 0]), 0.f);
        o0.y = fmaxf(fmaf(acc[1], nd, bias[c0 + 1]), 0.f);
        o0.z = fmaxf(fmaf(acc[2], nd, bias[c0 + 2]), 0.f);
        o0.w = fmaxf(fmaf(acc[3], nd, bias[c0 + 3]), 0.f);
        o1.x = fmaxf(fmaf(acc[4], nd, bias[c0 + 4]), 0.f);
        o1.y = fmaxf(fmaf(acc[5], nd, bias[c0 + 5]), 0.f);
        o1.z = fmaxf(fmaf(acc[6], nd, bias[c0 + 6]), 0.f);
        o1.w = fmaxf(fmaf(acc[7], nd, bias[c0 + 7]), 0.f);
        *(float4*)(out + (size_t)r * D + c0) = o0;
        *(float4*)(out + (size_t)r * D + c0 + 4) = o1;
    }
}

extern "C" void kernel_launch(void* const* d_in, const int* in_sizes, int n_in,
                              void* d_out, int out_size, void* d_ws, size_t ws_size,
                              hipStream_t stream) {
    const float* x  = (const float*)d_in[0];
    const float* ew = (const float*)d_in[1];
    const float* W0 = (const float*)d_in[2];
    const float* b0 = (const float*)d_in[3];
    const float* W1 = (const float*)d_in[4];
    const float* b1 = (const float*)d_in[5];
    const int* src  = (const int*)d_in[6];
    const int* dst  = (const int*)d_in[7];
    float* out = (float*)d_out;

    int n = in_sizes[0] / D;   // 10000
    int E = in_sizes[6];       // 640000
    if (n <= 0 || E <= 0) return;

    char* ws = (char*)d_ws;
    size_t off = 0;
    auto alloc = [&](size_t bytes) -> void* {
        void* p = ws + off;
        off = (off + bytes + 255) & ~(size_t)255;
        return p;
    };
    int* row_start  = (int*)alloc(((size_t)n + 1) * 4);
    int* in_deg     = (int*)alloc((size_t)n * 4);
    float* norm_src = (float*)alloc((size_t)n * 4);
    float* norm_dst = (float*)alloc((size_t)n * 4);
    int* qtot_d     = (int*)alloc((size_t)Q * n * 4);   // becomes qbase in finalize
    int* qtot_s     = (int*)alloc((size_t)Q * n * 4);
    size_t sorted_bytes = (size_t)E * 8;
    size_t ps_bytes = (size_t)NB * n * 2;
    int2* sorted    = (int2*)alloc(sorted_bytes > ps_bytes ? sorted_bytes : ps_bytes);
    float* B1       = (float*)alloc((size_t)n * D * 4);   // agg output
    float* B2       = (float*)alloc((size_t)n * D * 4);   // h1
    // pd (NB*n ushorts = 5.12 MB) aliases B1 (5.12 MB); consumed by fill before agg writes B1.
    unsigned short* pd = (unsigned short*)B1;
    // ps (NB*n ushorts) aliases sorted; consumed by colscan before fill writes sorted.
    unsigned short* ps = (unsigned short*)sorted;

    int nb = (n + 255) / 256;
    int qn = (n + 3) / 4;                  // nodes per quad
    int ab = 8 * ((qn + 3) / 4);           // 8 partition slots x groups of 4 nodes
    int gb = (n + TROWS - 1) / TROWS;

    hist_kernel<<<NB, 256, 0, stream>>>(src, dst, pd, ps, E, n);
    colscan_kernel<<<dim3(nb, Q), 256, 0, stream>>>(pd, ps, qtot_d, qtot_s, n);
    finalize_kernel<<<nb, 256, 0, stream>>>(qtot_d, qtot_s, in_deg, norm_src, norm_dst, n);
    scan_kernel<<<1, 1024, 0, stream>>>(in_deg, row_start, n);
    fill_kernel<<<NB, 256, 0, stream>>>(src, dst, ew, norm_src, row_start, qtot_d, pd, sorted, E, n);

    // layer 1: agg x (norm_src folded in records) -> B1, gemm -> B2
    agg_kernel<<<ab, 256, 0, stream>>>(x, row_start, sorted, B1, n, qn);
    gemm_kernel<<<gb, 256, 0, stream>>>(B1, W0, b0, norm_dst, B2, n);
    // layer 2: agg B2 -> B1, gemm -> out
    agg_kernel<<<ab, 256, 0, stream>>>(B2, row_start, sorted, B1, n, qn);
    gemm_kernel<<<gb, 256, 0, stream>>>(B1, W1, b1, norm_dst, out, n);
}